// Round 3
// baseline (11309.075 us; speedup 1.0000x reference)
//
#include <hip/hip_runtime.h>
#include <cstddef>
#include <cstdint>

#define TB 2048
#define CC 2048
#define BB 8
#define HH 32
#define BT (BB*TB)                       // 16384 rows
#define SLOT_E ((size_t)BT*CC)           // 33,554,432 elements

typedef unsigned short ushort_t;

// ---------------- bf16 helpers (bit-exact, RNE) ----------------------------
__device__ __forceinline__ float u2f(uint32_t b){ union{uint32_t u; float f;} c; c.u=b; return c.f; }
__device__ __forceinline__ uint32_t f2u(float f){ union{float f; uint32_t u;} c; c.f=f; return c.u; }
__device__ __forceinline__ float blo(uint32_t w){ return u2f(w << 16); }
__device__ __forceinline__ float bhi(uint32_t w){ return u2f(w & 0xffff0000u); }
__device__ __forceinline__ float bs(ushort_t v){ return u2f(((uint32_t)v) << 16); }
__device__ __forceinline__ uint32_t pack2(float a, float b){
    uint32_t ua = f2u(a), ub = f2u(b);
    uint32_t ra = (ua + 0x7fffu + ((ua >> 16) & 1u)) >> 16;
    uint32_t rb = (ub + 0x7fffu + ((ub >> 16) & 1u)) >> 16;
    return ra | (rb << 16);
}
__device__ __forceinline__ ushort_t f2b1(float f){
    uint32_t u = f2u(f);
    return (ushort_t)((u + 0x7fffu + ((u >> 16) & 1u)) >> 16);
}

// ---------------------------------------------------------------------------
// K1: xxx = x + (xprev - x)*maa_x  (bf16 out) ; x_last (fp32)
// ---------------------------------------------------------------------------
__global__ __launch_bounds__(256)
void prep_kernel(const float* __restrict__ x, const float* __restrict__ shift,
                 const float* __restrict__ maa_x,
                 ushort_t* __restrict__ xxx, float* __restrict__ xlast) {
    int gid = blockIdx.x * 256 + threadIdx.x;   // 8-elem chunk id
    int row = gid >> 8;                         // / (C/8)
    int c8  = gid & 255;
    int b = row >> 11, t = row & 2047;
    size_t off = (size_t)row * 2048 + c8 * 8;
    float4 xa = *(const float4*)(x + off);
    float4 xb = *(const float4*)(x + off + 4);
    const float* pp = (t == 0) ? shift + (size_t)b * 2048 + c8 * 8 : x + off - 2048;
    float4 pa = *(const float4*)pp;
    float4 pb = *(const float4*)(pp + 4);
    float4 ma = *(const float4*)(maa_x + c8 * 8);
    float4 mb = *(const float4*)(maa_x + c8 * 8 + 4);
    float o0 = xa.x + (pa.x - xa.x) * ma.x;
    float o1 = xa.y + (pa.y - xa.y) * ma.y;
    float o2 = xa.z + (pa.z - xa.z) * ma.z;
    float o3 = xa.w + (pa.w - xa.w) * ma.w;
    float o4 = xb.x + (pb.x - xb.x) * mb.x;
    float o5 = xb.y + (pb.y - xb.y) * mb.y;
    float o6 = xb.z + (pb.z - xb.z) * mb.z;
    float o7 = xb.w + (pb.w - xb.w) * mb.w;
    uint4 st; st.x = pack2(o0,o1); st.y = pack2(o2,o3);
    st.z = pack2(o4,o5); st.w = pack2(o6,o7);
    *(uint4*)(xxx + off) = st;
    if (t == 2047) {
        *(float4*)(xlast + (size_t)b * 2048 + c8 * 8)     = xa;
        *(float4*)(xlast + (size_t)b * 2048 + c8 * 8 + 4) = xb;
    }
}

// ---------------------------------------------------------------------------
// GEMM: C[M,N] = act(A_bf16[M,K] @ B_f32[K,N]) (+ C_old if ACCIN)
// 128x128 tile, 256 threads, 8x8 microtile, fp32 VALU compute.
// OUTF32: 1 -> fp32 C, 0 -> bf16 C.
// ---------------------------------------------------------------------------
template<int ACT, int OUTF32, int ACCIN>
__global__ __launch_bounds__(256)
void gemm_bf(const ushort_t* __restrict__ A, const float* __restrict__ B,
             void* __restrict__ Cv, int M, int N, int K) {
    __shared__ float As[16][136];   // [k][m]
    __shared__ float Bs[16][132];   // [k][n]
    const int tid = threadIdx.x;
    const int row0 = blockIdx.y * 128;
    const int col0 = blockIdx.x * 128;
    const int tx = tid & 15, ty = tid >> 4;
    const int aRow = tid >> 1, aK8 = (tid & 1) * 8;   // 8 bf16 (16B) per thread
    const int bK = tid >> 5, bN = (tid & 31) << 2;
    const bool bok = (col0 + bN) < N;                 // N%4==0
    const ushort_t* Ap = A + (size_t)(row0 + aRow) * K + aK8;
    const float* Bp0 = B + (size_t)bK * N + col0 + bN;
    const float* Bp1 = B + (size_t)(bK + 8) * N + col0 + bN;
    float acc[8][8] = {};
    for (int kt = 0; kt < K; kt += 16) {
        uint4 araw = *(const uint4*)(Ap + kt);        // 8 bf16
        float4 b0v = bok ? *(const float4*)(Bp0 + (size_t)kt * N) : make_float4(0,0,0,0);
        float4 b1v = bok ? *(const float4*)(Bp1 + (size_t)kt * N) : make_float4(0,0,0,0);
        __syncthreads();
        const uint32_t* ar = (const uint32_t*)&araw;
        #pragma unroll
        for (int q = 0; q < 4; ++q) {
            As[aK8 + q*2 + 0][aRow] = blo(ar[q]);
            As[aK8 + q*2 + 1][aRow] = bhi(ar[q]);
        }
        *(float4*)&Bs[bK][bN]   = b0v;
        *(float4*)&Bs[bK+8][bN] = b1v;
        __syncthreads();
        #pragma unroll
        for (int kk = 0; kk < 16; ++kk) {
            float4 x0 = *(const float4*)&As[kk][ty*8];
            float4 x1 = *(const float4*)&As[kk][ty*8+4];
            float4 y0 = *(const float4*)&Bs[kk][tx*8];
            float4 y1 = *(const float4*)&Bs[kk][tx*8+4];
            float av[8] = {x0.x,x0.y,x0.z,x0.w,x1.x,x1.y,x1.z,x1.w};
            float bv[8] = {y0.x,y0.y,y0.z,y0.w,y1.x,y1.y,y1.z,y1.w};
            #pragma unroll
            for (int i = 0; i < 8; ++i)
                #pragma unroll
                for (int j = 0; j < 8; ++j)
                    acc[i][j] += av[i] * bv[j];
        }
    }
    #pragma unroll
    for (int i = 0; i < 8; ++i) {
        int row = row0 + ty*8 + i;
        #pragma unroll
        for (int jh = 0; jh < 8; jh += 4) {
            int col = col0 + tx*8 + jh;
            if (col < N) {
                float r0 = acc[i][jh+0], r1 = acc[i][jh+1];
                float r2 = acc[i][jh+2], r3 = acc[i][jh+3];
                if (ACCIN) {
                    const ushort_t* cp = (const ushort_t*)Cv + (size_t)row * N + col;
                    uint2 old = *(const uint2*)cp;
                    r0 += blo(old.x); r1 += bhi(old.x);
                    r2 += blo(old.y); r3 += bhi(old.y);
                }
                if (ACT) { r0 = tanhf(r0); r1 = tanhf(r1); r2 = tanhf(r2); r3 = tanhf(r3); }
                if (OUTF32) {
                    float4 o; o.x = r0; o.y = r1; o.z = r2; o.w = r3;
                    *(float4*)((float*)Cv + (size_t)row * N + col) = o;
                } else {
                    uint2 st; st.x = pack2(r0, r1); st.y = pack2(r2, r3);
                    *(uint2*)((ushort_t*)Cv + (size_t)row * N + col) = st;
                }
            }
        }
    }
}

// ---------------------------------------------------------------------------
// K3: one gate per launch. xg = x + (xprev-x)*(maa_g + m_g),
// m_g[i,c] = sum_d mtan[i, G*32+d] * w2[G,d,c].  8 rows/block, 256 thr.
// ---------------------------------------------------------------------------
__global__ __launch_bounds__(256)
void mix_kernel(const float* __restrict__ x, const float* __restrict__ shift,
                const ushort_t* __restrict__ mtan, const float* __restrict__ w2,
                const float* __restrict__ maa_g, ushort_t* __restrict__ dst, int G) {
    __shared__ float ml[8][32];
    const int tid = threadIdx.x;
    const int rowbase = blockIdx.x * 8;
    {
        int rr = tid >> 5, d = tid & 31;
        ml[rr][d] = bs(mtan[(size_t)(rowbase + rr) * 160 + G*32 + d]);
    }
    __syncthreads();
    const int c0 = tid * 8;
    float acc[8][8] = {};
    for (int d = 0; d < 32; ++d) {
        const float* wp = w2 + ((size_t)(G*32 + d)) * 2048 + c0;
        float4 w0 = *(const float4*)wp;
        float4 w1 = *(const float4*)(wp + 4);
        float wv[8] = {w0.x,w0.y,w0.z,w0.w,w1.x,w1.y,w1.z,w1.w};
        #pragma unroll
        for (int rr = 0; rr < 8; ++rr) {
            float m = ml[rr][d];
            #pragma unroll
            for (int j = 0; j < 8; ++j) acc[rr][j] += m * wv[j];
        }
    }
    float4 m0 = *(const float4*)(maa_g + c0);
    float4 m1 = *(const float4*)(maa_g + c0 + 4);
    float mav[8] = {m0.x,m0.y,m0.z,m0.w,m1.x,m1.y,m1.z,m1.w};
    #pragma unroll
    for (int rr = 0; rr < 8; ++rr) {
        int rid = rowbase + rr;
        int b = rid >> 11, t = rid & 2047;
        size_t off = (size_t)rid * 2048 + c0;
        float4 xa = *(const float4*)(x + off);
        float4 xb = *(const float4*)(x + off + 4);
        const float* pp = (t == 0) ? shift + (size_t)b * 2048 + c0 : x + off - 2048;
        float4 pa = *(const float4*)pp;
        float4 pb = *(const float4*)(pp + 4);
        float xv[8] = {xa.x,xa.y,xa.z,xa.w,xb.x,xb.y,xb.z,xb.w};
        float pv[8] = {pa.x,pa.y,pa.z,pa.w,pb.x,pb.y,pb.z,pb.w};
        float o[8];
        #pragma unroll
        for (int j = 0; j < 8; ++j)
            o[j] = xv[j] + (pv[j] - xv[j]) * (mav[j] + acc[rr][j]);
        uint4 st; st.x = pack2(o[0],o[1]); st.y = pack2(o[2],o[3]);
        st.z = pack2(o[4],o[5]); st.w = pack2(o[6],o[7]);
        *(uint4*)(dst + off) = st;
    }
}

// ---------------------------------------------------------------------------
// K12: WKV scan. block=(b,h), 64 lanes; lane i owns S[k][i] column.
// w = lorat + tdecay[c]; d = exp(-exp(w)); keff = k*(1-d); u==0.
// y_t = r_t . S_t (pre-update), then S = d*S + keff*v.
// ---------------------------------------------------------------------------
__global__ __launch_bounds__(64)
void wkv_scan(const ushort_t* __restrict__ r, const ushort_t* __restrict__ k0,
              const ushort_t* __restrict__ wl, const float* __restrict__ tdecay,
              const ushort_t* __restrict__ v, const float* __restrict__ S0,
              ushort_t* __restrict__ y, float* __restrict__ Sout) {
    const int bh = blockIdx.x;
    const int b = bh >> 5, h = bh & 31;
    const int i = threadIdx.x;
    const float dec = tdecay[h*64 + i];
    __shared__ float lr[2][64], lk[2][64], ld[2][64];
    float s[64];
    const size_t sbase = (size_t)bh * 4096 + i;
    #pragma unroll
    for (int k = 0; k < 64; ++k) s[k] = S0[sbase + (size_t)k * 64];
    const size_t base = (size_t)b * TB * CC + (size_t)h * 64 + i;
    float rv = bs(r[base]), kv = bs(k0[base]), wv = bs(wl[base]), vv = bs(v[base]);
    int buf = 0;
    for (int t = 0; t < TB; ++t) {
        float rn = 0.f, kn = 0.f, wn = 0.f, vn = 0.f;
        if (t + 1 < TB) {                      // prefetch next step
            size_t off = base + (size_t)(t + 1) * CC;
            rn = bs(r[off]); kn = bs(k0[off]); wn = bs(wl[off]); vn = bs(v[off]);
        }
        float ddv = expf(-expf(wv + dec));
        lr[buf][i] = rv;
        lk[buf][i] = kv * (1.0f - ddv);
        ld[buf][i] = ddv;
        __syncthreads();
        float acc = 0.0f;
        #pragma unroll
        for (int k4 = 0; k4 < 16; ++k4) {
            float4 R  = *(const float4*)&lr[buf][k4*4];
            float4 Kk = *(const float4*)&lk[buf][k4*4];
            float4 D  = *(const float4*)&ld[buf][k4*4];
            acc += R.x * s[k4*4+0]; s[k4*4+0] = D.x * s[k4*4+0] + Kk.x * vv;
            acc += R.y * s[k4*4+1]; s[k4*4+1] = D.y * s[k4*4+1] + Kk.y * vv;
            acc += R.z * s[k4*4+2]; s[k4*4+2] = D.z * s[k4*4+2] + Kk.z * vv;
            acc += R.w * s[k4*4+3]; s[k4*4+3] = D.w * s[k4*4+3] + Kk.w * vv;
        }
        y[base + (size_t)t * CC] = f2b1(acc);
        rv = rn; kv = kn; wv = wn; vv = vn;
        buf ^= 1;
    }
    #pragma unroll
    for (int k = 0; k < 64; ++k) Sout[sbase + (size_t)k * 64] = s[k];
}

// ---------------------------------------------------------------------------
// K13: yt = y_scan + v2sum ; LayerNorm(yt)*ln_w + ln_b -> bf16
// ---------------------------------------------------------------------------
__device__ __forceinline__ float block_sum256(float v, float* red) {
    #pragma unroll
    for (int o = 32; o > 0; o >>= 1) v += __shfl_xor(v, o);
    __syncthreads();
    if ((threadIdx.x & 63) == 0) red[threadIdx.x >> 6] = v;
    __syncthreads();
    return (red[0] + red[1]) + (red[2] + red[3]);
}

__global__ __launch_bounds__(256)
void ln_fuse(const ushort_t* __restrict__ ys, const ushort_t* __restrict__ v2,
             const float* __restrict__ lnw, const float* __restrict__ lnb,
             ushort_t* __restrict__ out) {
    __shared__ float red[4];
    const int tid = threadIdx.x;
    const size_t base = (size_t)blockIdx.x * 2048 + tid * 8;
    uint4 ya = *(const uint4*)(ys + base);
    uint4 va = *(const uint4*)(v2 + base);
    const uint32_t* yw = (const uint32_t*)&ya;
    const uint32_t* vw = (const uint32_t*)&va;
    float vals[8];
    float ssum = 0.f;
    #pragma unroll
    for (int q = 0; q < 4; ++q) {
        vals[2*q+0] = blo(yw[q]) + blo(vw[q]);
        vals[2*q+1] = bhi(yw[q]) + bhi(vw[q]);
        ssum += vals[2*q+0] + vals[2*q+1];
    }
    float mu = block_sum256(ssum, red) * (1.0f / 2048.0f);
    float d2 = 0.f;
    #pragma unroll
    for (int j = 0; j < 8; ++j) { float d = vals[j] - mu; d2 += d * d; }
    float var = block_sum256(d2, red) * (1.0f / 2048.0f);
    float inv = 1.0f / sqrtf(var + 1e-5f);
    float o[8];
    #pragma unroll
    for (int u = 0; u < 2; ++u) {
        float4 w  = *(const float4*)(lnw + tid*8 + u*4);
        float4 bb = *(const float4*)(lnb + tid*8 + u*4);
        o[u*4+0] = (vals[u*4+0] - mu) * inv * w.x + bb.x;
        o[u*4+1] = (vals[u*4+1] - mu) * inv * w.y + bb.y;
        o[u*4+2] = (vals[u*4+2] - mu) * inv * w.z + bb.z;
        o[u*4+3] = (vals[u*4+3] - mu) * inv * w.w + bb.w;
    }
    uint4 st; st.x = pack2(o[0],o[1]); st.y = pack2(o[2],o[3]);
    st.z = pack2(o[4],o[5]); st.w = pack2(o[6],o[7]);
    *(uint4*)(out + base) = st;
}

// ---------------------------------------------------------------------------
extern "C" void kernel_launch(void* const* d_in, const int* in_sizes, int n_in,
                              void* d_out, int out_size, void* d_ws, size_t ws_size,
                              hipStream_t stream) {
    const float* x      = (const float*)d_in[0];
    const float* shift  = (const float*)d_in[1];
    const float* S0     = (const float*)d_in[2];
    const float* maa_x  = (const float*)d_in[3];
    const float* maa_r  = (const float*)d_in[4];
    const float* maa_k  = (const float*)d_in[5];
    const float* maa_v  = (const float*)d_in[6];
    const float* maa_w  = (const float*)d_in[7];
    const float* maa_v2 = (const float*)d_in[8];
    const float* maa_w1 = (const float*)d_in[9];
    const float* maa_w2 = (const float*)d_in[10];
    const float* tdecay = (const float*)d_in[11];
    const float* td_w1  = (const float*)d_in[12];
    const float* td_w2  = (const float*)d_in[13];
    const float* tv2_w1 = (const float*)d_in[14];
    const float* tv2_w2 = (const float*)d_in[15];
    const float* Wr     = (const float*)d_in[17];
    const float* Wk     = (const float*)d_in[18];
    const float* Wv     = (const float*)d_in[19];
    const float* Wo     = (const float*)d_in[20];
    const float* lnw    = (const float*)d_in[21];
    const float* lnb    = (const float*)d_in[22];

    // ws: exactly 4 bf16 slots (268,435,456 B)
    if (ws_size < 4 * SLOT_E * sizeof(ushort_t)) return;
    ushort_t* b0 = (ushort_t*)d_ws;          // xxx -> xw -> lorat
    ushort_t* b1 = b0 + SLOT_E;              // xv2 -> xr/xk/xv (transient) -> y_scan
    ushort_t* b2 = b1 + SLOT_E;              // r -> yn
    ushort_t* b3 = b2 + SLOT_E;              // k

    // out region aliasing
    float*    out_y = (float*)d_out;                 // final y (fp32) [BT*CC]
    ushort_t* o0    = (ushort_t*)d_out;              // v2sum (bf16)  [BT*CC]
    ushort_t* o1    = o0 + SLOT_E;                   // mtan, later v (bf16)
    ushort_t* mtan  = o1;                            // [BT*160] bf16 (head of o1)
    float*    outS  = out_y + SLOT_E;                // S_final (fp32) — scratch before scan:
    ushort_t* lw1   = (ushort_t*)outS;               //   [BT*64] bf16
    ushort_t* lv1   = lw1 + (size_t)BT * 64;         //   [BT*64] bf16
    float*    outX  = outS + (size_t)BB*HH*64*64;    // x[:,-1] (fp32)

    prep_kernel<<<16384, 256, 0, stream>>>(x, shift, maa_x, b0, outX);
    gemm_bf<1,0,0><<<dim3(2,128), 256, 0, stream>>>(b0, maa_w1, mtan, BT, 160, CC);
    mix_kernel<<<2048, 256, 0, stream>>>(x, shift, mtan, maa_w2, maa_w,  b0, 3); // xw
    mix_kernel<<<2048, 256, 0, stream>>>(x, shift, mtan, maa_w2, maa_v2, b1, 4); // xv2
    gemm_bf<1,0,0><<<dim3(1,128), 256, 0, stream>>>(b0, td_w1,  lw1, BT, 64, CC);
    gemm_bf<1,0,0><<<dim3(1,128), 256, 0, stream>>>(b1, tv2_w1, lv1, BT, 64, CC);
    gemm_bf<0,0,0><<<dim3(16,128), 256, 0, stream>>>(b1, Wv, o0, BT, CC, CC);     // v2a
    gemm_bf<0,0,1><<<dim3(16,128), 256, 0, stream>>>(lv1, tv2_w2, o0, BT, CC, 64);// += lorav2
    gemm_bf<0,0,0><<<dim3(16,128), 256, 0, stream>>>(lw1, td_w2, b0, BT, CC, 64); // lorat
    mix_kernel<<<2048, 256, 0, stream>>>(x, shift, mtan, maa_w2, maa_r, b1, 0);   // xr
    gemm_bf<0,0,0><<<dim3(16,128), 256, 0, stream>>>(b1, Wr, b2, BT, CC, CC);     // r
    mix_kernel<<<2048, 256, 0, stream>>>(x, shift, mtan, maa_w2, maa_k, b1, 1);   // xk
    gemm_bf<0,0,0><<<dim3(16,128), 256, 0, stream>>>(b1, Wk, b3, BT, CC, CC);     // k
    mix_kernel<<<2048, 256, 0, stream>>>(x, shift, mtan, maa_w2, maa_v, b1, 2);   // xv
    gemm_bf<0,0,0><<<dim3(16,128), 256, 0, stream>>>(b1, Wv, o1, BT, CC, CC);     // v (kills mtan)
    wkv_scan<<<256, 64, 0, stream>>>(b2, b3, b0, tdecay, o1, S0, b1, outS);       // y_scan->b1
    ln_fuse<<<16384, 256, 0, stream>>>(b1, o0, lnw, lnb, b2);                     // yn->b2
    gemm_bf<0,1,0><<<dim3(16,128), 256, 0, stream>>>(b2, Wo, out_y, BT, CC, CC);  // final
}